// Round 1
// baseline (389.568 us; speedup 1.0000x reference)
//
#include <hip/hip_runtime.h>
#include <hip/hip_bf16.h>
#include <stdint.h>

// Problem constants (PointerGenNetwork): T=64 B=32 S=400 V=32000 D=1536
#define T_DIM 64
#define B_DIM 32
#define S_DIM 400
#define V_DIM 32000
#define D_DIM 1536
#define M_DIM (T_DIM * B_DIM)   // 2048

typedef __attribute__((ext_vector_type(8))) short bf16x8;
typedef __attribute__((ext_vector_type(4))) float f32x4;

// ---------------- helpers ----------------

static __device__ __forceinline__ unsigned short f2bf(float x) {
    union { float f; uint32_t u; } v; v.f = x;
    // round-to-nearest-even f32 -> bf16 (inputs are finite normals)
    uint32_t r = (v.u + 0x7FFFu + ((v.u >> 16) & 1u)) >> 16;
    return (unsigned short)r;
}

static __device__ __forceinline__ void gload_lds16(const void* g, void* l) {
    __builtin_amdgcn_global_load_lds(
        (const __attribute__((address_space(1))) uint32_t*)g,
        (__attribute__((address_space(3))) uint32_t*)l,
        16, 0, 0);
}

// ---------------- pre-pass: h fp32 -> bf16 ----------------

__global__ void convert_h(const float* __restrict__ h, unsigned short* __restrict__ hb) {
    const size_t n4 = (size_t)M_DIM * D_DIM / 4;
    for (size_t i = (size_t)blockIdx.x * blockDim.x + threadIdx.x; i < n4;
         i += (size_t)gridDim.x * blockDim.x) {
        const float4 v = ((const float4*)h)[i];
        ushort4 o;
        o.x = f2bf(v.x); o.y = f2bf(v.y); o.z = f2bf(v.z); o.w = f2bf(v.w);
        ((ushort4*)hb)[i] = o;
    }
}

// ---------------- pre-pass: W (K x V fp32) -> Wt (V x K bf16) ----------------

__global__ __launch_bounds__(256)
void convT_W(const float* __restrict__ W, unsigned short* __restrict__ Wt) {
    __shared__ unsigned short lds[64 * 66];   // 64x64 tile, padded stride 66
    const int k0 = blockIdx.x * 64;           // 1536/64 = 24
    const int v0 = blockIdx.y * 64;           // 32000/64 = 500
    const int tid = threadIdx.x;
    const int rr = tid >> 4;                  // 0..15
    const int cc = (tid & 15) * 4;            // 0..60

    #pragma unroll
    for (int p = 0; p < 4; ++p) {
        const int r = p * 16 + rr;
        const float4 v = *(const float4*)&W[(size_t)(k0 + r) * V_DIM + v0 + cc];
        unsigned short* q = &lds[r * 66 + cc];
        q[0] = f2bf(v.x); q[1] = f2bf(v.y); q[2] = f2bf(v.z); q[3] = f2bf(v.w);
    }
    __syncthreads();
    #pragma unroll
    for (int p = 0; p < 4; ++p) {
        const int n = p * 16 + rr;
        ushort4 o;
        o.x = lds[(cc + 0) * 66 + n];
        o.y = lds[(cc + 1) * 66 + n];
        o.z = lds[(cc + 2) * 66 + n];
        o.w = lds[(cc + 3) * 66 + n];
        *(ushort4*)&Wt[(size_t)(v0 + n) * D_DIM + k0 + cc] = o;
    }
}

// ---------------- main GEMM: out[m][n] = pg[m] * (h@W + bias)[m][n] ----------------
// A: M x K bf16 row-major. Bt: N x K bf16 row-major (W transposed).
// 128x128 tile, BK=32, 4 waves (2x2), 16x16x32 bf16 MFMA, double-buffered LDS,
// global_load_lds width-16 staging (m97 structure).

#define BM 128
#define BN 128
#define BK 32
#define NKT (D_DIM / BK)   // 48

__global__ __launch_bounds__(256, 2)
void gemm_mfma(const unsigned short* __restrict__ A,
               const unsigned short* __restrict__ Bt,
               const float* __restrict__ bias,
               const float* __restrict__ p_gen,
               float* __restrict__ out) {
    __shared__ unsigned short lds[2][2][BM * BK];   // [buf][A=0/B=1], 8 KB each, 32 KB total

    const int bid = blockIdx.x;
    const int mt = bid & 15;        // 16 m-tiles (fastest -> W-panel reuse in L2/L3)
    const int nt = bid >> 4;        // 250 n-tiles
    const int m0 = mt * BM;
    const int n0 = nt * BN;
    const int tid = threadIdx.x;
    const int lane = tid & 63;
    const int wid = tid >> 6;
    const int wr = wid >> 1;        // wave row (0..1) -> 64 rows
    const int wc = wid & 1;         // wave col (0..1) -> 64 cols

    f32x4 acc[4][4] = {};

    // staging: tile = 128 rows x 64 bytes (32 bf16). o = tid*16 + i*4096.
    auto stage = [&](int buf, int kt) {
        const int k0 = kt * BK;
        #pragma unroll
        for (int i = 0; i < 2; ++i) {
            const int o = tid * 16 + i * 4096;
            const int row = o >> 6;
            const int colb = o & 63;
            const char* ga = (const char*)A + ((size_t)(m0 + row) * D_DIM + k0) * 2 + colb;
            gload_lds16(ga, (char*)&lds[buf][0][0] + o);
            const char* gb = (const char*)Bt + ((size_t)(n0 + row) * D_DIM + k0) * 2 + colb;
            gload_lds16(gb, (char*)&lds[buf][1][0] + o);
        }
    };

    const int kq = (lane >> 4) * 8;   // k offset within BK for this lane
    const int rq = lane & 15;         // row/col within 16-frag

    auto compute = [&](int buf) {
        const unsigned short* As = &lds[buf][0][0];
        const unsigned short* Bs = &lds[buf][1][0];
        bf16x8 a[4], b[4];
        #pragma unroll
        for (int i = 0; i < 4; ++i) {
            a[i] = *(const bf16x8*)&As[(wr * 64 + i * 16 + rq) * BK + kq];
            b[i] = *(const bf16x8*)&Bs[(wc * 64 + i * 16 + rq) * BK + kq];
        }
        #pragma unroll
        for (int mi = 0; mi < 4; ++mi)
            #pragma unroll
            for (int ni = 0; ni < 4; ++ni)
                acc[mi][ni] = __builtin_amdgcn_mfma_f32_16x16x32_bf16(a[mi], b[ni], acc[mi][ni], 0, 0, 0);
    };

    stage(0, 0);
    int cur = 0;
    for (int kt = 0; kt < NKT; ++kt) {
        __syncthreads();                     // drains staging vmcnt + protects buffer reuse
        if (kt + 1 < NKT) stage(cur ^ 1, kt + 1);
        compute(cur);
        cur ^= 1;
    }

    // epilogue: C/D layout col=lane&15, row=(lane>>4)*4+reg
    const int rr4 = (lane >> 4) * 4;
    #pragma unroll
    for (int mi = 0; mi < 4; ++mi) {
        #pragma unroll
        for (int r = 0; r < 4; ++r) {
            const int m = m0 + wr * 64 + mi * 16 + rr4 + r;
            const float pg = p_gen[m];
            #pragma unroll
            for (int ni = 0; ni < 4; ++ni) {
                const int n = n0 + wc * 64 + ni * 16 + rq;
                out[(size_t)m * V_DIM + n] = pg * (acc[mi][ni][r] + bias[n]);
            }
        }
    }
}

// ---------------- scatter: out[t,b,post[s,b]] += (1-pg[t,b]) * att[t,b,s] ----------------

__global__ void scatter_att(const float* __restrict__ att, const float* __restrict__ p_gen,
                            const int* __restrict__ post, float* __restrict__ out) {
    const int tb = blockIdx.x;             // t*B + b
    const int b = tb & (B_DIM - 1);
    const float g = 1.0f - p_gen[tb];
    float* o = out + (size_t)tb * V_DIM;
    const float* a = att + (size_t)tb * S_DIM;
    for (int s = threadIdx.x; s < S_DIM; s += blockDim.x) {
        atomicAdd(&o[post[s * B_DIM + b]], g * a[s]);
    }
}

// ---------------- fallback (ws too small): fp32 vector GEMM ----------------

#define FB_MT 16
__global__ __launch_bounds__(256)
void gemm_naive(const float* __restrict__ h, const float* __restrict__ W,
                const float* __restrict__ bias, const float* __restrict__ pg,
                float* __restrict__ out) {
    const int mb = blockIdx.y;                         // M/16 = 128
    const int v = blockIdx.x * 256 + threadIdx.x;      // V/256 = 125
    __shared__ float hs[FB_MT][128];
    float acc[FB_MT] = {};
    for (int k0 = 0; k0 < D_DIM; k0 += 128) {
        for (int i = threadIdx.x; i < FB_MT * 128; i += 256)
            hs[i >> 7][i & 127] = h[(size_t)(mb * FB_MT + (i >> 7)) * D_DIM + k0 + (i & 127)];
        __syncthreads();
        for (int kk = 0; kk < 128; ++kk) {
            const float wv = W[(size_t)(k0 + kk) * V_DIM + v];
            #pragma unroll
            for (int i = 0; i < FB_MT; ++i) acc[i] += hs[i][kk] * wv;
        }
        __syncthreads();
    }
    #pragma unroll
    for (int i = 0; i < FB_MT; ++i) {
        const int m = mb * FB_MT + i;
        out[(size_t)m * V_DIM + v] = pg[m] * (acc[i] + bias[v]);
    }
}

// ---------------- launcher ----------------

extern "C" void kernel_launch(void* const* d_in, const int* in_sizes, int n_in,
                              void* d_out, int out_size, void* d_ws, size_t ws_size,
                              hipStream_t stream) {
    const float* h    = (const float*)d_in[0];   // (T,B,D)
    const float* W    = (const float*)d_in[1];   // (D,V)
    const float* bias = (const float*)d_in[2];   // (V,)
    const float* att  = (const float*)d_in[3];   // (T,B,S)
    const float* pg   = (const float*)d_in[4];   // (T,B,1)
    const int*   post = (const int*)d_in[5];     // (S,B)
    float* out = (float*)d_out;                  // (T,B,V) fp32

    const size_t wt_bytes = (size_t)V_DIM * D_DIM * 2;   // 98,304,000
    const size_t hb_bytes = (size_t)M_DIM * D_DIM * 2;   //  6,291,456

    if (ws_size >= wt_bytes + hb_bytes) {
        unsigned short* Wt = (unsigned short*)d_ws;
        unsigned short* hb = (unsigned short*)((char*)d_ws + wt_bytes);
        convert_h<<<1024, 256, 0, stream>>>(h, hb);
        dim3 tg(D_DIM / 64, V_DIM / 64);   // 24 x 500
        convT_W<<<tg, 256, 0, stream>>>(W, Wt);
        gemm_mfma<<<16 * 250, 256, 0, stream>>>(hb, Wt, bias, pg, out);
    } else {
        dim3 fg(V_DIM / 256, M_DIM / FB_MT);   // 125 x 128
        gemm_naive<<<fg, 256, 0, stream>>>(h, W, bias, pg, out);
    }

    scatter_att<<<M_DIM, 256, 0, stream>>>(att, pg, post, out);
}